// Round 4
// baseline (830.002 us; speedup 1.0000x reference)
//
#include <hip/hip_runtime.h>
#include <math.h>

// Problem constants
#define NB 2048   // batch
#define NIN 512   // input width
#define NK 16     // K (patch/channel width)
#define NL 497    // L = IN - K + 1
#define NT 96     // decode steps
#define NREP 32   // BN accumulator replicas

// ---------- math helpers ----------
__device__ __forceinline__ float gelu_exact(float x) {
    return 0.5f * x * (1.0f + erff(x * 0.70710678118654752440f));
}
__device__ __forceinline__ float gate_act(float acc, bool isG) {
    float mm = isG ? 2.0f : 1.0f;
    float e  = __expf(-mm * acc);
    float s  = 1.0f / (1.0f + e);
    return isG ? 2.0f * s - 1.0f : s;
}
__device__ __forceinline__ float tanh_safe(float x) {
    float t = __expf(-2.0f * fabsf(x));
    float r = 1.0f - 2.0f * t / (1.0f + t);
    return copysignf(r, x);
}
// pull-shuffle: result = src value of lane (idxb/4). idxb precomputed in bytes.
__device__ __forceinline__ float bperm(int idxb, float v) {
    return __int_as_float(__builtin_amdgcn_ds_bpermute(idxb, __float_as_int(v)));
}
__device__ __forceinline__ void load16(const float* __restrict__ ptr, float* dst) {
    const float4* rp = (const float4*)ptr;
    float4 a = rp[0], b = rp[1], c = rp[2], d = rp[3];
    dst[0]=a.x; dst[1]=a.y; dst[2]=a.z;  dst[3]=a.w;
    dst[4]=b.x; dst[5]=b.y; dst[6]=b.z;  dst[7]=b.w;
    dst[8]=c.x; dst[9]=c.y; dst[10]=c.z; dst[11]=c.w;
    dst[12]=d.x;dst[13]=d.y;dst[14]=d.z; dst[15]=d.w;
}

// ---------- K1: patch + seg matmul + gelu + BN sums (+ optional LSTM input projections) ----------
// p16[b,l,k] = gelu( (x-patch + pe) @ Wseg^T + bseg )
// PRAW: praw[(b,l, 0..31)] = p16 . Wf0[g,:]  ; praw[(b, NL-1-l, 32..63)] = p16 . Wb0[g,:]
//       (bwd gates stored l-reversed so the bwd sweep walks ASCENDING addresses)
template<int PRAW>
__global__ __launch_bounds__(256) void k_seg(
    const float* __restrict__ x, const float* __restrict__ pe,
    const float* __restrict__ Wseg, const float* __restrict__ bseg,
    const float* __restrict__ Wf0, const float* __restrict__ Wb0,
    float* __restrict__ praw, float* __restrict__ pfull,
    float* __restrict__ p_last, float* __restrict__ bn)
{
    __shared__ float xs[NIN];
    __shared__ float wsg[NK * NK];
    __shared__ float bs[NK];
    __shared__ float wf[32 * 16];
    __shared__ float wb[32 * 16];
    const int tid = threadIdx.x;
    const int b = blockIdx.x;
    float* bnr = bn + (size_t)(b & (NREP - 1)) * 1024;
    for (int i = tid; i < NIN; i += 256) xs[i] = x[(size_t)b * NIN + i];
    if (tid < NK * NK) wsg[tid] = Wseg[tid];
    if (tid < NK) bs[tid] = bseg[tid];
    if constexpr (PRAW) {
        for (int i = tid; i < 512; i += 256) { wf[i] = Wf0[i]; wb[i] = Wb0[i]; }
    }
    __syncthreads();

    for (int l = tid; l < NL; l += 256) {
        float u[NK];
        load16(pe + l * NK, u);
        #pragma unroll
        for (int k = 0; k < NK; k++) u[k] += xs[l + k];
        float p16[NK];
        float s = 0.f, s2 = 0.f;
        #pragma unroll
        for (int k = 0; k < NK; k++) {
            float acc = bs[k];
            #pragma unroll
            for (int kp = 0; kp < NK; kp++) acc += u[kp] * wsg[k * NK + kp];
            float gv = gelu_exact(acc);
            p16[k] = gv; s += gv; s2 += gv * gv;
        }
        atomicAdd(&bnr[l], s);
        atomicAdd(&bnr[512 + l], s2);

        if constexpr (PRAW) {
            float* pf = praw + ((size_t)b * NL + l) * 64;                   // fwd gates
            float* pb = praw + ((size_t)b * NL + (NL - 1 - l)) * 64 + 32;   // bwd gates, reversed
            #pragma unroll 2
            for (int gq = 0; gq < 8; gq++) {
                float4 o;
                float* op = (float*)&o;
                #pragma unroll
                for (int q = 0; q < 4; q++) {
                    const float* wr = &wf[(gq * 4 + q) * 16];
                    float a0 = 0.f;
                    #pragma unroll
                    for (int k = 0; k < 16; k++) a0 += p16[k] * wr[k];
                    op[q] = a0;
                }
                ((float4*)pf)[gq] = o;
            }
            #pragma unroll 2
            for (int gq = 0; gq < 8; gq++) {
                float4 o;
                float* op = (float*)&o;
                #pragma unroll
                for (int q = 0; q < 4; q++) {
                    const float* wr = &wb[(gq * 4 + q) * 16];
                    float a0 = 0.f;
                    #pragma unroll
                    for (int k = 0; k < 16; k++) a0 += p16[k] * wr[k];
                    op[q] = a0;
                }
                ((float4*)pb)[gq] = o;
            }
        } else {
            float4* pr = (float4*)(pfull + ((size_t)b * NL + l) * NK);
            pr[0] = make_float4(p16[0], p16[1], p16[2], p16[3]);
            pr[1] = make_float4(p16[4], p16[5], p16[6], p16[7]);
            pr[2] = make_float4(p16[8], p16[9], p16[10], p16[11]);
            pr[3] = make_float4(p16[12], p16[13], p16[14], p16[15]);
        }
        if (l == NL - 1) {
            float4* pl = (float4*)(p_last + (size_t)b * NK);
            pl[0] = make_float4(p16[0], p16[1], p16[2], p16[3]);
            pl[1] = make_float4(p16[4], p16[5], p16[6], p16[7]);
            pl[2] = make_float4(p16[8], p16[9], p16[10], p16[11]);
            pl[3] = make_float4(p16[12], p16[13], p16[14], p16[15]);
        }
    }
}

// ---------- K2: finalize BN -> ansh4[l] = {a_f(l), sh_f(l), a_b(l)=a[NL-1-l], sh_b(l)} ----------
// Both sweep directions read ansh4 with ASCENDING step index s and get a[t], sh[t].
__global__ void k_bnfin(const float* __restrict__ bn, const float* __restrict__ gbn,
                        const float* __restrict__ bbn, float* __restrict__ ansh4)
{
    int l = blockIdx.x * blockDim.x + threadIdx.x;
    if (l < NL) {
        float s = 0.f, s2 = 0.f;
        #pragma unroll 4
        for (int r = 0; r < NREP; r++) {
            s  += bn[(size_t)r * 1024 + l];
            s2 += bn[(size_t)r * 1024 + 512 + l];
        }
        const float inv = 1.0f / (float)(NB * NK);
        float mu  = s * inv;
        float var = s2 * inv - mu * mu;
        float rr  = rsqrtf(var + 1e-5f);
        float av  = gbn[l] * rr;
        float sh  = bbn[l] - mu * av;
        ansh4[4 * l]     = av;
        ansh4[4 * l + 1] = sh;
        int lr = NL - 1 - l;
        ansh4[4 * lr + 2] = av;
        ansh4[4 * lr + 3] = sh;
    }
}

// ---------- K3: bidirectional LSTM sweep ----------
// One wave per batch element; lanes 0-31 fwd cell, 32-63 bwd cell.
// lane = 32*d + g, gates [i(0-7) f(8-15) g(16-23) o(24-31)], j = g&7.
// MODE 0: input from praw (precomputed projections, 1 dword/lane/step) + BN affine.
// MODE 1: input from p rows (16-dot) + BN affine (fallback when ws too small for praw).
// MODE 2: input from o0 rows (16-dot), no BN (layer 1).
template<int MODE, int WRITE_O, int WRITE_LAST>
__global__ __launch_bounds__(256) void k_lstm(
    const float* __restrict__ src, const float* __restrict__ ansh4,
    const float* __restrict__ WihF, const float* __restrict__ WhhF,
    const float* __restrict__ WihB, const float* __restrict__ WhhB,
    float* __restrict__ oout, float* __restrict__ st, float* __restrict__ oblast)
{
    const int tid = threadIdx.x;
    const int lane = tid & 63;
    const int b = blockIdx.x * 4 + (tid >> 6);
    const int d = lane >> 5, g = lane & 31, j = g & 7;
    const int base = d << 5;
    const float* Wih = d ? WihB : WihF;
    const float* Whh = d ? WhhB : WhhF;

    float whh[8];
    #pragma unroll
    for (int k = 0; k < 8; k++) whh[k] = Whh[g * 8 + k];

    float wih[16];
    float Sg = 0.f;
    if constexpr (MODE != 0) {
        #pragma unroll
        for (int k = 0; k < 16; k++) wih[k] = Wih[g * 16 + k];
    }
    if constexpr (MODE == 0) {
        #pragma unroll
        for (int k = 0; k < 16; k++) Sg += Wih[g * 16 + k];
    } else if constexpr (MODE == 1) {
        #pragma unroll
        for (int k = 0; k < 16; k++) Sg += wih[k];
    }

    // loop-invariant bpermute byte indices
    int pidx[8];
    #pragma unroll
    for (int k = 0; k < 8; k++) pidx[k] = (base + k) << 2;
    const int gF = (base + j + 8) << 2;
    const int gG = (base + j + 16) << 2;
    const int gO = (base + j + 24) << 2;

    float hb[8];
    #pragma unroll
    for (int k = 0; k < 8; k++) hb[k] = 0.f;
    float h = 0.f, c = 0.f;
    const bool isG = (g >= 16) && (g < 24);
    const bool keep = (g < 8);

    const int t0 = d ? NL - 1 : 0;
    // o0 store pointer (walked)
    float* po = nullptr;
    const int dstore = d ? -NK : NK;
    if constexpr (WRITE_O) po = oout + ((size_t)b * NL + t0) * NK + (d << 3) + j;

    // cell step: acc already contains the input contribution
    auto cell = [&](float acc, int s) {
        acc += (whh[0] * hb[0] + whh[1] * hb[1]) + (whh[2] * hb[2] + whh[3] * hb[3])
             + (whh[4] * hb[4] + whh[5] * hb[5]) + (whh[6] * hb[6] + whh[7] * hb[7]);
        float val = gate_act(acc, isG);
        float fv = bperm(gF, val);
        float gv = bperm(gG, val);
        float ov = bperm(gO, val);
        float cn = fv * c + val * gv;     // valid for keep lanes
        float hn = ov * tanh_safe(cn);
        if (keep) { c = cn; h = hn; }
        #pragma unroll
        for (int k = 0; k < 8; k++) hb[k] = bperm(pidx[k], hn);   // reads lanes base+0..7 (valid)
        if constexpr (WRITE_O) {
            if (keep) *po = hn;
            po += dstore;
        }
        if constexpr (WRITE_LAST) {
            if (s == 0 && d == 1 && keep) oblast[b * 8 + j] = hn;
        }
    };

    if constexpr (MODE == 0) {
        // praw: both halves walk ascending (bwd gates stored l-reversed by k_seg)
        const float* pr = src + ((size_t)b * NL) * 64 + base + g;     // element (b, s=0, d*32+g)
        const float2* pa2 = (const float2*)ansh4 + (d ? 1 : 0);       // reads pa2[2s]
        int s = 0;
        for (int blk = 0; blk < 62; blk++) {                          // 62*8 = 496 steps
            #pragma unroll
            for (int u = 0; u < 8; u++) {
                float pv = pr[(size_t)(u * 64)];
                float2 as = pa2[2 * u];
                cell(as.x * pv + as.y * Sg, s + u);
            }
            pr += 512; pa2 += 16; s += 8;
        }
        { float pv = pr[0]; float2 as = pa2[0]; cell(as.x * pv + as.y * Sg, s); }  // s=496
    } else {
        // row-wise input (p or o0), 4-deep rotation, walked per-half row pointer
        const float* rp = src + ((size_t)b * NL + t0) * NK;
        const int drow = d ? -NK : NK;
        const float2* pa2 = (const float2*)ansh4 + (d ? 1 : 0);
        auto dostep = [&](int s, const float* B) {
            float acc = (B[0]*wih[0] + B[1]*wih[1]) + (B[2]*wih[2] + B[3]*wih[3])
                      + (B[4]*wih[4] + B[5]*wih[5]) + (B[6]*wih[6] + B[7]*wih[7])
                      + (B[8]*wih[8] + B[9]*wih[9]) + (B[10]*wih[10] + B[11]*wih[11])
                      + (B[12]*wih[12] + B[13]*wih[13]) + (B[14]*wih[14] + B[15]*wih[15]);
            if constexpr (MODE == 1) {
                float2 as = pa2[0]; pa2 += 2;
                acc = as.x * acc + as.y * Sg;
            }
            cell(acc, s);
        };
        float B0[16], B1[16], B2[16], B3[16];
        load16(rp, B0); rp += drow;
        load16(rp, B1); rp += drow;
        load16(rp, B2); rp += drow;
        int s = 0;
        for (; s + 4 <= NL; s += 4) {
            load16(rp, B3); rp += drow; dostep(s + 0, B0);
            load16(rp, B0); rp += drow; dostep(s + 1, B1);
            load16(rp, B1); rp += drow; dostep(s + 2, B2);
            load16(rp, B2); rp += drow; dostep(s + 3, B3);
        }
        if (s     < NL) dostep(s,     B0);
        if (s + 1 < NL) dostep(s + 1, B1);
        if (s + 2 < NL) dostep(s + 2, B2);
    }

    if (keep) {
        float* hs = st + (d ? (size_t)2 * NB * 8 : 0);
        hs[b * 8 + j] = h;
        hs[(size_t)NB * 8 + b * 8 + j] = c;
    }
}

// ---------- K4: 96-step decode recurrence ----------
__global__ __launch_bounds__(256) void k_dec(
    const float* __restrict__ Wf0, const float* __restrict__ Uf0,
    const float* __restrict__ Wb0, const float* __restrict__ Ub0,
    const float* __restrict__ Wf1, const float* __restrict__ Uf1,
    const float* __restrict__ Wb1, const float* __restrict__ Ub1,
    const float* __restrict__ st0, const float* __restrict__ st1,
    const float* __restrict__ oblast, const float* __restrict__ p_last,
    const float* __restrict__ ansh4,
    const float* __restrict__ gln, const float* __restrict__ bln,
    float* __restrict__ z)
{
    const int tid = threadIdx.x, lane = tid & 63;
    const int b = blockIdx.x * 4 + (tid >> 6);
    const int d = lane >> 5, g = lane & 31, j = g & 7, base = d << 5;
    const float* Wih0 = d ? Wb0 : Wf0; const float* Whh0 = d ? Ub0 : Uf0;
    const float* Wih1 = d ? Wb1 : Wf1; const float* Whh1 = d ? Ub1 : Uf1;
    float wih0[16], whh0[8], wih1[16], whh1[8];
    #pragma unroll
    for (int k = 0; k < 16; k++) { wih0[k] = Wih0[g * 16 + k]; wih1[k] = Wih1[g * 16 + k]; }
    #pragma unroll
    for (int k = 0; k < 8; k++)  { whh0[k] = Whh0[g * 8 + k]; whh1[k] = Whh1[g * 8 + k]; }

    float h0 = 0.f, c0 = 0.f, h1 = 0.f, c1 = 0.f;
    const bool keep = (g < 8);
    if (keep) {
        const float* s0 = st0 + (d ? (size_t)2 * NB * 8 : 0);
        h0 = s0[b * 8 + j]; c0 = s0[(size_t)NB * 8 + b * 8 + j];
        const float* s1 = st1 + (d ? (size_t)2 * NB * 8 : 0);
        h1 = s1[b * 8 + j]; c1 = s1[(size_t)NB * 8 + b * 8 + j];
    }

    // broadcast initial states: m0 = concat(hf0, hb0) wave-wide; hb0/hb1 = own-half 8
    float m0[16], fbh[16], hb0[8], hb1[8];
    #pragma unroll
    for (int k = 0; k < 16; k++) m0[k]  = bperm(((k < 8) ? k : 24 + k) << 2, h0);
    #pragma unroll
    for (int k = 0; k < 16; k++) fbh[k] = bperm(((k < 8) ? k : 24 + k) << 2, h1);
    #pragma unroll
    for (int k = 0; k < 8; k++) { hb0[k] = d ? m0[8 + k] : m0[k]; hb1[k] = d ? fbh[8 + k] : fbh[k]; }

    // fb = LN(concat(hf1_final, ob1_last)) * g_ln + b_ln + xe[:,L-1,:]
    float fb[16];
    {
        float ol[16];
        #pragma unroll
        for (int k = 0; k < 8; k++) ol[k] = st1[b * 8 + k];
        #pragma unroll
        for (int k = 0; k < 8; k++) ol[8 + k] = oblast[b * 8 + k];
        float mn = 0.f;
        #pragma unroll
        for (int k = 0; k < 16; k++) mn += ol[k];
        mn *= (1.0f / 16.0f);
        float vv = 0.f;
        #pragma unroll
        for (int k = 0; k < 16; k++) { float dq = ol[k] - mn; vv += dq * dq; }
        vv *= (1.0f / 16.0f);
        float rr = rsqrtf(vv + 1e-5f);
        float aL = ansh4[4 * (NL - 1)], sL = ansh4[4 * (NL - 1) + 1];
        const float* prow = p_last + (size_t)b * NK;
        #pragma unroll
        for (int k = 0; k < 16; k++)
            fb[k] = (ol[k] - mn) * rr * gln[k] + bln[k] + (prow[k] * aL + sL);
    }

    const bool isG = (g >= 16) && (g < 24);
    const int gF = (base + j + 8) << 2;
    const int gG = (base + j + 16) << 2;
    const int gO = (base + j + 24) << 2;
    float* pz = z + ((size_t)b * NT) * NK + (d << 3) + j;

    for (int t = 0; t < NT; t++) {
        // layer-0 cell
        float acc = (fb[0]*wih0[0] + fb[1]*wih0[1]) + (fb[2]*wih0[2] + fb[3]*wih0[3])
                  + (fb[4]*wih0[4] + fb[5]*wih0[5]) + (fb[6]*wih0[6] + fb[7]*wih0[7])
                  + (fb[8]*wih0[8] + fb[9]*wih0[9]) + (fb[10]*wih0[10] + fb[11]*wih0[11])
                  + (fb[12]*wih0[12] + fb[13]*wih0[13]) + (fb[14]*wih0[14] + fb[15]*wih0[15]);
        acc += (whh0[0]*hb0[0] + whh0[1]*hb0[1]) + (whh0[2]*hb0[2] + whh0[3]*hb0[3])
             + (whh0[4]*hb0[4] + whh0[5]*hb0[5]) + (whh0[6]*hb0[6] + whh0[7]*hb0[7]);
        float val = gate_act(acc, isG);
        float fv = bperm(gF, val), gv = bperm(gG, val), ov = bperm(gO, val);
        float cn = fv * c0 + val * gv;
        float hn = ov * tanh_safe(cn);
        if (keep) { c0 = cn; h0 = hn; }
        #pragma unroll
        for (int k = 0; k < 16; k++) m0[k] = bperm(((k < 8) ? k : 24 + k) << 2, hn);
        #pragma unroll
        for (int k = 0; k < 8; k++) hb0[k] = d ? m0[8 + k] : m0[k];
        // layer-1 cell
        acc = (m0[0]*wih1[0] + m0[1]*wih1[1]) + (m0[2]*wih1[2] + m0[3]*wih1[3])
            + (m0[4]*wih1[4] + m0[5]*wih1[5]) + (m0[6]*wih1[6] + m0[7]*wih1[7])
            + (m0[8]*wih1[8] + m0[9]*wih1[9]) + (m0[10]*wih1[10] + m0[11]*wih1[11])
            + (m0[12]*wih1[12] + m0[13]*wih1[13]) + (m0[14]*wih1[14] + m0[15]*wih1[15]);
        acc += (whh1[0]*hb1[0] + whh1[1]*hb1[1]) + (whh1[2]*hb1[2] + whh1[3]*hb1[3])
             + (whh1[4]*hb1[4] + whh1[5]*hb1[5]) + (whh1[6]*hb1[6] + whh1[7]*hb1[7]);
        val = gate_act(acc, isG);
        fv = bperm(gF, val); gv = bperm(gG, val); ov = bperm(gO, val);
        cn = fv * c1 + val * gv;
        hn = ov * tanh_safe(cn);
        if (keep) { c1 = cn; h1 = hn; *pz = hn; }
        pz += NK;
        #pragma unroll
        for (int k = 0; k < 16; k++) fb[k] = bperm(((k < 8) ? k : 24 + k) << 2, hn);
        #pragma unroll
        for (int k = 0; k < 8; k++) hb1[k] = d ? fb[8 + k] : fb[k];
    }
}

// ---------- K5: decoder MLP over all (b,t) rows ----------
__global__ __launch_bounds__(256) void k_head(
    const float* __restrict__ z, const float* __restrict__ gln, const float* __restrict__ bln,
    const float* __restrict__ W1, const float* __restrict__ b1,
    const float* __restrict__ W2, const float* __restrict__ b2,
    float* __restrict__ outp)
{
    __shared__ float w1s[512 * 16];
    __shared__ float b1s[512];
    __shared__ float w2s[512];
    const int tid = threadIdx.x;
    for (int i = tid; i < 512 * 16 / 4; i += 256)
        ((float4*)w1s)[i] = ((const float4*)W1)[i];
    for (int i = tid; i < 512; i += 256) { b1s[i] = b1[i]; w2s[i] = W2[i]; }
    __syncthreads();

    const size_t r = (size_t)blockIdx.x * 256 + tid;   // r = b*NT + t
    float zr[16];
    load16(z + r * 16, zr);
    float mn = 0.f;
    #pragma unroll
    for (int k = 0; k < 16; k++) mn += zr[k];
    mn *= (1.0f / 16.0f);
    float vv = 0.f;
    #pragma unroll
    for (int k = 0; k < 16; k++) { float dq = zr[k] - mn; vv += dq * dq; }
    vv *= (1.0f / 16.0f);
    float rr = rsqrtf(vv + 1e-5f);
    float zn[16];
    #pragma unroll
    for (int k = 0; k < 16; k++) zn[k] = (zr[k] - mn) * rr * gln[k] + bln[k];

    float y = b2[0];
    #pragma unroll 2
    for (int i = 0; i < 512; i++) {
        const float4* w4 = (const float4*)&w1s[i * 16];
        float4 wa = w4[0], wb = w4[1], wc = w4[2], wd = w4[3];
        float acc = b1s[i];
        acc += zn[0]*wa.x + zn[1]*wa.y + zn[2]*wa.z + zn[3]*wa.w;
        acc += zn[4]*wb.x + zn[5]*wb.y + zn[6]*wb.z + zn[7]*wb.w;
        acc += zn[8]*wc.x + zn[9]*wc.y + zn[10]*wc.z + zn[11]*wc.w;
        acc += zn[12]*wd.x + zn[13]*wd.y + zn[14]*wd.z + zn[15]*wd.w;
        y += gelu_exact(acc) * w2s[i];
    }
    outp[r] = y;
}

// ---------- launcher ----------
extern "C" void kernel_launch(void* const* d_in, const int* in_sizes, int n_in,
                              void* d_out, int out_size, void* d_ws, size_t ws_size,
                              hipStream_t stream)
{
    const float* x    = (const float*)d_in[0];
    const float* pe   = (const float*)d_in[1];
    const float* Wseg = (const float*)d_in[2];
    const float* bseg = (const float*)d_in[3];
    const float* gbn  = (const float*)d_in[4];
    const float* bbn  = (const float*)d_in[5];
    const float* Wf0  = (const float*)d_in[6];
    const float* Uf0  = (const float*)d_in[7];
    const float* Wb0  = (const float*)d_in[8];
    const float* Ub0  = (const float*)d_in[9];
    const float* Wf1  = (const float*)d_in[10];
    const float* Uf1  = (const float*)d_in[11];
    const float* Wb1  = (const float*)d_in[12];
    const float* Ub1  = (const float*)d_in[13];
    const float* gln  = (const float*)d_in[14];
    const float* bln  = (const float*)d_in[15];
    const float* W1   = (const float*)d_in[16];
    const float* b1   = (const float*)d_in[17];
    const float* W2   = (const float*)d_in[18];
    const float* b2   = (const float*)d_in[19];

    const size_t SZ_BN    = (size_t)NREP * 1024 * 4;
    const size_t SZ_ANSH  = (size_t)4 * 512 * 4;
    const size_t SZ_ST    = (size_t)4 * NB * 8 * 4;
    const size_t SZ_OBL   = (size_t)NB * 8 * 4;
    const size_t SZ_PLAST = (size_t)NB * NK * 4;
    const size_t SZ_Z     = (size_t)NB * NT * NK * 4;
    const size_t SZ_O0    = (size_t)NB * NL * NK * 4;
    const size_t SZ_PRAW  = (size_t)NB * NL * 64 * 4;
    const size_t GUARD    = 8192;

    char* ws = (char*)d_ws;
    size_t off = 0;
    auto take = [&](size_t bytes) -> char* {
        char* r = ws + off;
        off = (off + bytes + 255) & ~(size_t)255;
        return r;
    };
    float* bn     = (float*)take(SZ_BN);
    float* ansh4  = (float*)take(SZ_ANSH);
    float* st0    = (float*)take(SZ_ST);
    float* st1    = (float*)take(SZ_ST);
    float* obl    = (float*)take(SZ_OBL);
    float* p_last = (float*)take(SZ_PLAST);
    float* z      = (float*)take(SZ_Z);

    const size_t fixed = off;
    const size_t need_slim = fixed + SZ_O0 + SZ_PRAW + GUARD + 2048;
    const bool slim = (ws_size >= need_slim);

    hipMemsetAsync(bn, 0, SZ_BN, stream);

    if (slim) {
        float* o0   = (float*)take(SZ_O0);
        float* praw = (float*)take(SZ_PRAW);
        (void)take(GUARD);
        k_seg<1><<<NB, 256, 0, stream>>>(x, pe, Wseg, bseg, Wf0, Wb0, praw, nullptr, p_last, bn);
        k_bnfin<<<2, 256, 0, stream>>>(bn, gbn, bbn, ansh4);
        k_lstm<0, 1, 0><<<NB / 4, 256, 0, stream>>>(praw, ansh4, Wf0, Uf0, Wb0, Ub0, o0, st0, nullptr);
        k_lstm<2, 0, 1><<<NB / 4, 256, 0, stream>>>(o0, ansh4, Wf1, Uf1, Wb1, Ub1, nullptr, st1, obl);
    } else {
        float* p  = (float*)take(SZ_O0);   // p rows (b,l,16)
        float* o0 = (float*)take(SZ_O0);
        (void)take(GUARD);
        k_seg<0><<<NB, 256, 0, stream>>>(x, pe, Wseg, bseg, Wf0, Wb0, nullptr, p, p_last, bn);
        k_bnfin<<<2, 256, 0, stream>>>(bn, gbn, bbn, ansh4);
        k_lstm<1, 1, 0><<<NB / 4, 256, 0, stream>>>(p, ansh4, Wf0, Uf0, Wb0, Ub0, o0, st0, nullptr);
        k_lstm<2, 0, 1><<<NB / 4, 256, 0, stream>>>(o0, ansh4, Wf1, Uf1, Wb1, Ub1, nullptr, st1, obl);
    }
    // o0 pointer for the second lstm is whichever was allocated in the chosen branch;
    // recompute deterministically for k_dec/k_head inputs (they don't need o0).
    k_dec<<<NB / 4, 256, 0, stream>>>(Wf0, Uf0, Wb0, Ub0, Wf1, Uf1, Wb1, Ub1,
                                      st0, st1, obl, p_last, ansh4, gln, bln, z);
    k_head<<<(NB * NT) / 256, 256, 0, stream>>>(z, gln, bln, W1, b1, W2, b2, (float*)d_out);
}

// Round 7
// 734.196 us; speedup vs baseline: 1.1305x; 1.1305x over previous
//
#include <hip/hip_runtime.h>
#include <math.h>

// Problem constants
#define NB 2048   // batch
#define NIN 512   // input width
#define NK 16     // K (patch/channel width)
#define NL 497    // L = IN - K + 1
#define NT 96     // decode steps
#define NREP 32   // BN accumulator replicas

// ---------- math helpers ----------
__device__ __forceinline__ float gelu_exact(float x) {
    return 0.5f * x * (1.0f + erff(x * 0.70710678118654752440f));
}
__device__ __forceinline__ float gate_act(float acc, bool isG) {
    float mm = isG ? 2.0f : 1.0f;
    float e  = __expf(-mm * acc);
    float s  = 1.0f / (1.0f + e);
    return isG ? 2.0f * s - 1.0f : s;
}
__device__ __forceinline__ float tanh_safe(float x) {
    float t = __expf(-2.0f * fabsf(x));
    float r = 1.0f - 2.0f * t / (1.0f + t);
    return copysignf(r, x);
}
__device__ __forceinline__ void load16(const float* __restrict__ ptr, float* dst) {
    const float4* rp = (const float4*)ptr;
    float4 a = rp[0], b = rp[1], c = rp[2], d = rp[3];
    dst[0]=a.x; dst[1]=a.y; dst[2]=a.z;  dst[3]=a.w;
    dst[4]=b.x; dst[5]=b.y; dst[6]=b.z;  dst[7]=b.w;
    dst[8]=c.x; dst[9]=c.y; dst[10]=c.z; dst[11]=c.w;
    dst[12]=d.x;dst[13]=d.y;dst[14]=d.z; dst[15]=d.w;
}

// ---------- K1: patch + seg matmul + gelu + BN sums (+ optional layer-0 input projections) ----------
// p16[b,l,k] = gelu( (x-patch + pe) @ Wseg^T + bseg )
// PRAW: praw[(b,l, 0..31)] = p16 . Wf0[g,:] ; praw[(b, NL-1-l, 32..63)] = p16 . Wb0[g,:]
//       (bwd gates stored l-reversed so the bwd sweep walks ASCENDING addresses)
template<int PRAW>
__global__ __launch_bounds__(256) void k_seg(
    const float* __restrict__ x, const float* __restrict__ pe,
    const float* __restrict__ Wseg, const float* __restrict__ bseg,
    const float* __restrict__ Wf0, const float* __restrict__ Wb0,
    float* __restrict__ praw, float* __restrict__ pfull,
    float* __restrict__ p_last, float* __restrict__ bn)
{
    __shared__ float xs[NIN];
    __shared__ float wsg[NK * NK];
    __shared__ float bs[NK];
    __shared__ float wf[32 * 16];
    __shared__ float wb[32 * 16];
    const int tid = threadIdx.x;
    const int b = blockIdx.x;
    float* bnr = bn + (size_t)(b & (NREP - 1)) * 1024;
    for (int i = tid; i < NIN; i += 256) xs[i] = x[(size_t)b * NIN + i];
    if (tid < NK * NK) wsg[tid] = Wseg[tid];
    if (tid < NK) bs[tid] = bseg[tid];
    if constexpr (PRAW) {
        for (int i = tid; i < 512; i += 256) { wf[i] = Wf0[i]; wb[i] = Wb0[i]; }
    }
    __syncthreads();

    for (int l = tid; l < NL; l += 256) {
        float u[NK];
        load16(pe + l * NK, u);
        #pragma unroll
        for (int k = 0; k < NK; k++) u[k] += xs[l + k];
        float p16[NK];
        float s = 0.f, s2 = 0.f;
        #pragma unroll
        for (int k = 0; k < NK; k++) {
            float acc = bs[k];
            #pragma unroll
            for (int kp = 0; kp < NK; kp++) acc += u[kp] * wsg[k * NK + kp];
            float gv = gelu_exact(acc);
            p16[k] = gv; s += gv; s2 += gv * gv;
        }
        atomicAdd(&bnr[l], s);
        atomicAdd(&bnr[512 + l], s2);

        if constexpr (PRAW) {
            float* pf = praw + ((size_t)b * NL + l) * 64;                   // fwd gates
            float* pb = praw + ((size_t)b * NL + (NL - 1 - l)) * 64 + 32;   // bwd gates, reversed
            #pragma unroll 2
            for (int gq = 0; gq < 8; gq++) {
                float4 o;
                float* op = (float*)&o;
                #pragma unroll
                for (int q = 0; q < 4; q++) {
                    const float* wr = &wf[(gq * 4 + q) * 16];
                    float a0 = 0.f;
                    #pragma unroll
                    for (int k = 0; k < 16; k++) a0 += p16[k] * wr[k];
                    op[q] = a0;
                }
                ((float4*)pf)[gq] = o;
            }
            #pragma unroll 2
            for (int gq = 0; gq < 8; gq++) {
                float4 o;
                float* op = (float*)&o;
                #pragma unroll
                for (int q = 0; q < 4; q++) {
                    const float* wr = &wb[(gq * 4 + q) * 16];
                    float a0 = 0.f;
                    #pragma unroll
                    for (int k = 0; k < 16; k++) a0 += p16[k] * wr[k];
                    op[q] = a0;
                }
                ((float4*)pb)[gq] = o;
            }
        } else {
            float4* pr = (float4*)(pfull + ((size_t)b * NL + l) * NK);
            pr[0] = make_float4(p16[0], p16[1], p16[2], p16[3]);
            pr[1] = make_float4(p16[4], p16[5], p16[6], p16[7]);
            pr[2] = make_float4(p16[8], p16[9], p16[10], p16[11]);
            pr[3] = make_float4(p16[12], p16[13], p16[14], p16[15]);
        }
        if (l == NL - 1) {
            float4* pl = (float4*)(p_last + (size_t)b * NK);
            pl[0] = make_float4(p16[0], p16[1], p16[2], p16[3]);
            pl[1] = make_float4(p16[4], p16[5], p16[6], p16[7]);
            pl[2] = make_float4(p16[8], p16[9], p16[10], p16[11]);
            pl[3] = make_float4(p16[12], p16[13], p16[14], p16[15]);
        }
    }
}

// ---------- K2: finalize BN -> ansh4 pairs: pair[2l+0]={a_f(l),sh_f(l)}, pair[2l+1]={a_b(l),sh_b(l)} ----------
// a_b(s) = a(NL-1-s): both directions read pair[2s+d] with ASCENDING step s.
__global__ void k_bnfin(const float* __restrict__ bn, const float* __restrict__ gbn,
                        const float* __restrict__ bbn, float* __restrict__ ansh4)
{
    int l = blockIdx.x * blockDim.x + threadIdx.x;
    if (l < NL) {
        float s = 0.f, s2 = 0.f;
        #pragma unroll 4
        for (int r = 0; r < NREP; r++) {
            s  += bn[(size_t)r * 1024 + l];
            s2 += bn[(size_t)r * 1024 + 512 + l];
        }
        const float inv = 1.0f / (float)(NB * NK);
        float mu  = s * inv;
        float var = s2 * inv - mu * mu;
        float rr  = rsqrtf(var + 1e-5f);
        float av  = gbn[l] * rr;
        float sh  = bbn[l] - mu * av;
        ansh4[4 * l]     = av;
        ansh4[4 * l + 1] = sh;
        int lr = NL - 1 - l;
        ansh4[4 * lr + 2] = av;
        ansh4[4 * lr + 3] = sh;
    }
}

// ---------- K3: bidirectional LSTM sweep (round-3 shfl cell) ----------
// One wave per batch element; lanes 0-31 fwd cell, 32-63 bwd cell.
// lane = 32*d + g, gates [i(0-7) f(8-15) g(16-23) o(24-31)], j = g&7.
// MODE 0: input from praw (precomputed projections, 1 dword/lane/step) + BN affine.
// MODE 1: input from p rows (16-dot) + BN affine (fallback when ws too small for praw).
// MODE 2: input from o0 rows (16-dot), no BN (layer 1).
template<int MODE, int WRITE_O, int WRITE_LAST>
__global__ __launch_bounds__(256) void k_lstm(
    const float* __restrict__ src, const float* __restrict__ ansh4,
    const float* __restrict__ WihF, const float* __restrict__ WhhF,
    const float* __restrict__ WihB, const float* __restrict__ WhhB,
    float* __restrict__ oout, float* __restrict__ st, float* __restrict__ oblast)
{
    const int tid = threadIdx.x;
    const int lane = tid & 63;
    const int b = blockIdx.x * 4 + (tid >> 6);
    const int d = lane >> 5, g = lane & 31, j = g & 7;
    const int base = d << 5;
    const float* Wih = d ? WihB : WihF;
    const float* Whh = d ? WhhB : WhhF;

    float whh[8];
    #pragma unroll
    for (int k = 0; k < 8; k++) whh[k] = Whh[g * 8 + k];

    float wih[16];
    float Sg = 0.f;
    if constexpr (MODE != 0) {
        #pragma unroll
        for (int k = 0; k < 16; k++) wih[k] = Wih[g * 16 + k];
        #pragma unroll
        for (int k = 0; k < 16; k++) Sg += wih[k];
    } else {
        #pragma unroll
        for (int k = 0; k < 16; k++) Sg += Wih[g * 16 + k];
    }

    float h = 0.f, c = 0.f;
    const bool isG = (g >= 16) && (g < 24);

    // round-3 cell: shfl with constant offsets, acc contains input contribution
    auto cell = [&](float acc, int s) {
        #pragma unroll
        for (int k = 0; k < 8; k++) acc += whh[k] * __shfl(h, base + k, 64);
        float val = gate_act(acc, isG);
        float fv = __shfl(val, lane + 8, 64);
        float gv = __shfl(val, lane + 16, 64);
        float ov = __shfl(val, lane + 24, 64);
        float cn = fv * c + val * gv;      // valid for g<8 (val = sigmoid(i))
        float hn = ov * tanh_safe(cn);
        if (g < 8) { c = cn; h = hn; }
        if constexpr (WRITE_O) {
            const int t = d ? (NL - 1 - s) : s;
            if (g < 8) oout[((size_t)b * NL + t) * NK + (d << 3) + j] = hn;
        }
        if constexpr (WRITE_LAST) {
            if (s == 0 && d == 1 && g < 8) oblast[b * 8 + j] = hn;
        }
    };

    if constexpr (MODE == 0) {
        // praw: both halves walk ascending (bwd gates stored l-reversed by k_seg).
        // per step: 1 dword (praw) + 1 float2 (ansh pair). 4-deep scalar rotation.
        // Tail loads overrun by <=2 rows (512 B) into the guard region — values unused.
        const float* pr = src + (size_t)b * NL * 64 + lane;
        const float2* pa = (const float2*)ansh4 + d;   // pa[2s] = (a,sh) for step s, this dir
        float P0, P1, P2, P3;
        float2 A0, A1, A2, A3;
        P0 = pr[0];   A0 = pa[0];
        P1 = pr[64];  A1 = pa[2];
        P2 = pr[128]; A2 = pa[4];
        pr += 192; pa += 6;
        int s = 0;
        for (; s + 4 <= NL; s += 4) {
            P3 = pr[0];   A3 = pa[0]; cell(A0.x * P0 + A0.y * Sg, s);
            P0 = pr[64];  A0 = pa[2]; cell(A1.x * P1 + A1.y * Sg, s + 1);
            P1 = pr[128]; A1 = pa[4]; cell(A2.x * P2 + A2.y * Sg, s + 2);
            P2 = pr[192]; A2 = pa[6]; cell(A3.x * P3 + A3.y * Sg, s + 3);
            pr += 256; pa += 8;
        }
        if (s     < NL) cell(A0.x * P0 + A0.y * Sg, s);
        if (s + 1 < NL) cell(A1.x * P1 + A1.y * Sg, s + 1);
        if (s + 2 < NL) cell(A2.x * P2 + A2.y * Sg, s + 2);
    } else {
        // row-wise input (p or o0), round-3 4-deep pipeline with clamped indexed loads
        const float* srcb = src + (size_t)b * NL * NK;
        auto rowt = [&](int sp) -> int {
            int t = d ? (NL - 1 - sp) : sp;
            t = t < 0 ? 0 : t;
            t = t > NL - 1 ? NL - 1 : t;
            return t;
        };
        auto ld = [&](int sp, float* dst, float2& a) {
            const int t = rowt(sp);
            load16(srcb + (size_t)t * NK, dst);
            if constexpr (MODE == 1) {
                int sc = sp > NL - 1 ? NL - 1 : sp;
                a = ((const float2*)ansh4)[2 * sc + d];
            }
        };
        auto stp = [&](int s, const float* B, float2 a) {
            float acc = 0.f;
            #pragma unroll
            for (int k = 0; k < 16; k++) acc += B[k] * wih[k];
            if constexpr (MODE == 1) acc = a.x * acc + a.y * Sg;
            cell(acc, s);
        };
        float B0[16], B1[16], B2[16], B3[16];
        float2 A0{0,0}, A1{0,0}, A2{0,0}, A3{0,0};
        ld(0, B0, A0); ld(1, B1, A1); ld(2, B2, A2);
        int s = 0;
        for (; s + 4 <= NL; s += 4) {
            ld(s + 3, B3, A3); stp(s + 0, B0, A0);
            ld(s + 4, B0, A0); stp(s + 1, B1, A1);
            ld(s + 5, B1, A1); stp(s + 2, B2, A2);
            ld(s + 6, B2, A2); stp(s + 3, B3, A3);
        }
        if (s     < NL) stp(s,     B0, A0);
        if (s + 1 < NL) stp(s + 1, B1, A1);
        if (s + 2 < NL) stp(s + 2, B2, A2);
    }

    if (g < 8) {
        float* hs = st + (d ? (size_t)2 * NB * 8 : 0);
        hs[b * 8 + j] = h;
        hs[(size_t)NB * 8 + b * 8 + j] = c;
    }
}

// ---------- K4: 96-step decode recurrence (round-3 shfl version) ----------
__global__ __launch_bounds__(256) void k_dec(
    const float* __restrict__ Wf0, const float* __restrict__ Uf0,
    const float* __restrict__ Wb0, const float* __restrict__ Ub0,
    const float* __restrict__ Wf1, const float* __restrict__ Uf1,
    const float* __restrict__ Wb1, const float* __restrict__ Ub1,
    const float* __restrict__ st0, const float* __restrict__ st1,
    const float* __restrict__ oblast, const float* __restrict__ p_last,
    const float* __restrict__ ansh4,
    const float* __restrict__ gln, const float* __restrict__ bln,
    float* __restrict__ z)
{
    const int tid = threadIdx.x, lane = tid & 63;
    const int b = blockIdx.x * 4 + (tid >> 6);
    const int d = lane >> 5, g = lane & 31, j = g & 7, base = d << 5;
    const float* Wih0 = d ? Wb0 : Wf0; const float* Whh0 = d ? Ub0 : Uf0;
    const float* Wih1 = d ? Wb1 : Wf1; const float* Whh1 = d ? Ub1 : Uf1;
    float wih0[16], whh0[8], wih1[16], whh1[8];
    #pragma unroll
    for (int k = 0; k < 16; k++) { wih0[k] = Wih0[g * 16 + k]; wih1[k] = Wih1[g * 16 + k]; }
    #pragma unroll
    for (int k = 0; k < 8; k++)  { whh0[k] = Whh0[g * 8 + k]; whh1[k] = Whh1[g * 8 + k]; }

    float h0 = 0.f, c0 = 0.f, h1 = 0.f, c1 = 0.f;
    if (g < 8) {
        const float* s0 = st0 + (d ? (size_t)2 * NB * 8 : 0);
        h0 = s0[b * 8 + j]; c0 = s0[(size_t)NB * 8 + b * 8 + j];
        const float* s1 = st1 + (d ? (size_t)2 * NB * 8 : 0);
        h1 = s1[b * 8 + j]; c1 = s1[(size_t)NB * 8 + b * 8 + j];
    }

    // fb = LN(concat(hf1_final, ob1_last)) * g_ln + b_ln + xe[:,L-1,:]
    float fb[16];
    {
        float ol[16];
        #pragma unroll
        for (int k = 0; k < 8; k++) ol[k] = st1[b * 8 + k];          // hF1 final == of1[:,L-1]
        #pragma unroll
        for (int k = 0; k < 8; k++) ol[8 + k] = oblast[b * 8 + k];   // ob1[:,L-1]
        float mn = 0.f;
        #pragma unroll
        for (int k = 0; k < 16; k++) mn += ol[k];
        mn *= (1.0f / 16.0f);
        float vv = 0.f;
        #pragma unroll
        for (int k = 0; k < 16; k++) { float dq = ol[k] - mn; vv += dq * dq; }
        vv *= (1.0f / 16.0f);
        float rr = rsqrtf(vv + 1e-5f);
        float aL = ansh4[4 * (NL - 1)], sL = ansh4[4 * (NL - 1) + 1];
        const float* prow = p_last + (size_t)b * NK;
        #pragma unroll
        for (int k = 0; k < 16; k++)
            fb[k] = (ol[k] - mn) * rr * gln[k] + bln[k] + (prow[k] * aL + sL);
    }

    const bool isG = (g >= 16) && (g < 24);
    for (int t = 0; t < NT; t++) {
        // layer-0 cell
        float acc = 0.f;
        #pragma unroll
        for (int k = 0; k < 16; k++) acc += fb[k] * wih0[k];
        #pragma unroll
        for (int k = 0; k < 8; k++) acc += whh0[k] * __shfl(h0, base + k, 64);
        float val = gate_act(acc, isG);
        float fv = __shfl(val, lane + 8, 64);
        float gv = __shfl(val, lane + 16, 64);
        float ov = __shfl(val, lane + 24, 64);
        float cn = fv * c0 + val * gv;
        float hn = ov * tanh_safe(cn);
        if (g < 8) { c0 = cn; h0 = hn; }
        // m0 = concat(hf0, hb0) broadcast to all lanes
        float m0[16];
        #pragma unroll
        for (int k = 0; k < 16; k++) m0[k] = __shfl(h0, k < 8 ? k : 24 + k, 64);
        // layer-1 cell
        acc = 0.f;
        #pragma unroll
        for (int k = 0; k < 16; k++) acc += m0[k] * wih1[k];
        #pragma unroll
        for (int k = 0; k < 8; k++) acc += whh1[k] * __shfl(h1, base + k, 64);
        val = gate_act(acc, isG);
        fv = __shfl(val, lane + 8, 64);
        gv = __shfl(val, lane + 16, 64);
        ov = __shfl(val, lane + 24, 64);
        cn = fv * c1 + val * gv;
        hn = ov * tanh_safe(cn);
        if (g < 8) { c1 = cn; h1 = hn; }
        if (g < 8) z[((size_t)b * NT + t) * NK + (d << 3) + j] = hn;
        // new fb = raw o = concat(hf1, hb1)
        #pragma unroll
        for (int k = 0; k < 16; k++) fb[k] = __shfl(h1, k < 8 ? k : 24 + k, 64);
    }
}

// ---------- K5: decoder MLP over all (b,t) rows ----------
__global__ __launch_bounds__(256) void k_head(
    const float* __restrict__ z, const float* __restrict__ gln, const float* __restrict__ bln,
    const float* __restrict__ W1, const float* __restrict__ b1,
    const float* __restrict__ W2, const float* __restrict__ b2,
    float* __restrict__ outp)
{
    __shared__ float w1s[512 * 16];
    __shared__ float b1s[512];
    __shared__ float w2s[512];
    const int tid = threadIdx.x;
    for (int i = tid; i < 512 * 16 / 4; i += 256)
        ((float4*)w1s)[i] = ((const float4*)W1)[i];
    for (int i = tid; i < 512; i += 256) { b1s[i] = b1[i]; w2s[i] = W2[i]; }
    __syncthreads();

    const size_t r = (size_t)blockIdx.x * 256 + tid;   // r = b*NT + t
    float zr[16];
    load16(z + r * 16, zr);
    float mn = 0.f;
    #pragma unroll
    for (int k = 0; k < 16; k++) mn += zr[k];
    mn *= (1.0f / 16.0f);
    float vv = 0.f;
    #pragma unroll
    for (int k = 0; k < 16; k++) { float dq = zr[k] - mn; vv += dq * dq; }
    vv *= (1.0f / 16.0f);
    float rr = rsqrtf(vv + 1e-5f);
    float zn[16];
    #pragma unroll
    for (int k = 0; k < 16; k++) zn[k] = (zr[k] - mn) * rr * gln[k] + bln[k];

    float y = b2[0];
    #pragma unroll 2
    for (int i = 0; i < 512; i++) {
        const float4* w4 = (const float4*)&w1s[i * 16];
        float4 wa = w4[0], wb = w4[1], wc = w4[2], wd = w4[3];
        float acc = b1s[i];
        acc += zn[0]*wa.x + zn[1]*wa.y + zn[2]*wa.z + zn[3]*wa.w;
        acc += zn[4]*wb.x + zn[5]*wb.y + zn[6]*wb.z + zn[7]*wb.w;
        acc += zn[8]*wc.x + zn[9]*wc.y + zn[10]*wc.z + zn[11]*wc.w;
        acc += zn[12]*wd.x + zn[13]*wd.y + zn[14]*wd.z + zn[15]*wd.w;
        y += gelu_exact(acc) * w2s[i];
    }
    outp[r] = y;
}

// ---------- launcher ----------
extern "C" void kernel_launch(void* const* d_in, const int* in_sizes, int n_in,
                              void* d_out, int out_size, void* d_ws, size_t ws_size,
                              hipStream_t stream)
{
    const float* x    = (const float*)d_in[0];
    const float* pe   = (const float*)d_in[1];
    const float* Wseg = (const float*)d_in[2];
    const float* bseg = (const float*)d_in[3];
    const float* gbn  = (const float*)d_in[4];
    const float* bbn  = (const float*)d_in[5];
    const float* Wf0  = (const float*)d_in[6];
    const float* Uf0  = (const float*)d_in[7];
    const float* Wb0  = (const float*)d_in[8];
    const float* Ub0  = (const float*)d_in[9];
    const float* Wf1  = (const float*)d_in[10];
    const float* Uf1  = (const float*)d_in[11];
    const float* Wb1  = (const float*)d_in[12];
    const float* Ub1  = (const float*)d_in[13];
    const float* gln  = (const float*)d_in[14];
    const float* bln  = (const float*)d_in[15];
    const float* W1   = (const float*)d_in[16];
    const float* b1   = (const float*)d_in[17];
    const float* W2   = (const float*)d_in[18];
    const float* b2   = (const float*)d_in[19];

    const size_t SZ_BN    = (size_t)NREP * 1024 * 4;
    const size_t SZ_ANSH  = (size_t)4 * 512 * 4;
    const size_t SZ_ST    = (size_t)4 * NB * 8 * 4;
    const size_t SZ_OBL   = (size_t)NB * 8 * 4;
    const size_t SZ_PLAST = (size_t)NB * NK * 4;
    const size_t SZ_Z     = (size_t)NB * NT * NK * 4;
    const size_t SZ_O0    = (size_t)NB * NL * NK * 4;
    const size_t SZ_PRAW  = (size_t)NB * NL * 64 * 4;
    const size_t GUARD    = 8192;

    char* ws = (char*)d_ws;
    size_t off = 0;
    auto take = [&](size_t bytes) -> char* {
        char* r = ws + off;
        off = (off + bytes + 255) & ~(size_t)255;
        return r;
    };
    float* bn     = (float*)take(SZ_BN);
    float* ansh4  = (float*)take(SZ_ANSH);
    float* st0    = (float*)take(SZ_ST);
    float* st1    = (float*)take(SZ_ST);
    float* obl    = (float*)take(SZ_OBL);
    float* p_last = (float*)take(SZ_PLAST);
    float* z      = (float*)take(SZ_Z);

    const size_t fixed = off;
    const size_t need_slim = fixed + SZ_O0 + SZ_PRAW + GUARD + 2048;
    const bool slim = (ws_size >= need_slim);

    hipMemsetAsync(bn, 0, SZ_BN, stream);

    if (slim) {
        float* o0   = (float*)take(SZ_O0);
        float* praw = (float*)take(SZ_PRAW);
        (void)take(GUARD);
        k_seg<1><<<NB, 256, 0, stream>>>(x, pe, Wseg, bseg, Wf0, Wb0, praw, nullptr, p_last, bn);
        k_bnfin<<<2, 256, 0, stream>>>(bn, gbn, bbn, ansh4);
        k_lstm<0, 1, 0><<<NB / 4, 256, 0, stream>>>(praw, ansh4, Wf0, Uf0, Wb0, Ub0, o0, st0, nullptr);
        k_lstm<2, 0, 1><<<NB / 4, 256, 0, stream>>>(o0, ansh4, Wf1, Uf1, Wb1, Ub1, nullptr, st1, obl);
    } else {
        float* p  = (float*)take(SZ_O0);   // p rows (b,l,16)
        float* o0 = (float*)take(SZ_O0);
        (void)take(GUARD);
        k_seg<0><<<NB, 256, 0, stream>>>(x, pe, Wseg, bseg, Wf0, Wb0, nullptr, p, p_last, bn);
        k_bnfin<<<2, 256, 0, stream>>>(bn, gbn, bbn, ansh4);
        k_lstm<1, 1, 0><<<NB / 4, 256, 0, stream>>>(p, ansh4, Wf0, Uf0, Wb0, Ub0, o0, st0, nullptr);
        k_lstm<2, 0, 1><<<NB / 4, 256, 0, stream>>>(o0, ansh4, Wf1, Uf1, Wb1, Ub1, nullptr, st1, obl);
    }
    k_dec<<<NB / 4, 256, 0, stream>>>(Wf0, Uf0, Wb0, Ub0, Wf1, Uf1, Wb1, Ub1,
                                      st0, st1, obl, p_last, ansh4, gln, bln, z);
    k_head<<<(NB * NT) / 256, 256, 0, stream>>>(z, gln, bln, W1, b1, W2, b2, (float*)d_out);
}